// Round 7
// baseline (461.787 us; speedup 1.0000x reference)
//
#include <hip/hip_runtime.h>
#include <hip/hip_bf16.h>
#include <hip/hip_fp16.h>

// GCN: out = softmax( GCNConv2( relu( GCNConv1(x) ) ) )
// GCNConv(x) = D^-1/2 (A+I) D^-1/2 (x W) + b
//
// Round 7:
//  (a) R6 post-mortem: fill_csr_x WRITE_SIZE stayed 72 MB because each XCD
//      streams the full 12.8 MB edge list through its 4 MB L2, evicting the
//      partially-filled csr lines. Fix: __builtin_nontemporal_load on the
//      edge-list reads (deg_count_x / fill_csr_x) so the 0.85 MB csr+cursor
//      region stays L2-resident and lines write back full.
//  (b) gather inner loops: ILP 4 -> 8 (premult made them pure load+add;
//      avg deg 16 = two 8-wide iterations, deeper MLP vs ~500cyc LLC latency).

#define K_DIM 128

__global__ __launch_bounds__(256) void zero_int(int* p, int n) {
    int i = blockIdx.x * 256 + threadIdx.x;
    if (i < n) p[i] = 0;
}

// XCD-bucketed degree count: block handles dst range (blockIdx&7); edge-list
// reads are non-temporal so deg region stays in L2.
__global__ __launch_bounds__(256) void deg_count_x(const int* __restrict__ dst, int E,
                                                   int nper, int* __restrict__ deg) {
    const int r = blockIdx.x & 7;
    const int e = (blockIdx.x >> 3) * 256 + threadIdx.x;
    if (e >= E) return;
    const int d = __builtin_nontemporal_load(&dst[e]);
    if ((unsigned)(d - r * nper) < (unsigned)nper) atomicAdd(&deg[d], 1);
}

// ---- parallel exclusive scan of deg (N elements) ----
__global__ __launch_bounds__(256) void block_sums(const int* __restrict__ deg, int n,
                                                  int* __restrict__ bsum) {
    const int i = blockIdx.x * 256 + threadIdx.x;
    int v = (i < n) ? deg[i] : 0;
    #pragma unroll
    for (int off = 32; off; off >>= 1) v += __shfl_xor(v, off, 64);
    __shared__ int ws[4];
    const int lane = threadIdx.x & 63, wid = threadIdx.x >> 6;
    if (lane == 0) ws[wid] = v;
    __syncthreads();
    if (threadIdx.x == 0) bsum[blockIdx.x] = ws[0] + ws[1] + ws[2] + ws[3];
}

__global__ __launch_bounds__(1024) void scan_bsums(int* __restrict__ bsum, int nb,
                                                   int* __restrict__ rowptr, int n) {
    __shared__ int part[1024];
    const int t = threadIdx.x;
    const int chunk = (nb + 1023) >> 10;
    const int s = t * chunk;
    const int e = (s + chunk < nb) ? (s + chunk) : nb;
    int sum = 0;
    for (int i = s; i < e; ++i) sum += bsum[i];
    part[t] = sum;
    __syncthreads();
    for (int off = 1; off < 1024; off <<= 1) {
        int u = (t >= off) ? part[t - off] : 0;
        __syncthreads();
        part[t] += u;
        __syncthreads();
    }
    int run = part[t] - sum;
    for (int i = s; i < e; ++i) { int v = bsum[i]; bsum[i] = run; run += v; }
    if (t == 1023) rowptr[n] = part[1023];     // == E
}

__global__ __launch_bounds__(256) void scan_write(const int* __restrict__ deg,
                                                  const int* __restrict__ bsum, int n,
                                                  int* __restrict__ rowptr,
                                                  int* __restrict__ cursor,
                                                  float* __restrict__ norm) {
    const int i = blockIdx.x * 256 + threadIdx.x;
    const int lane = threadIdx.x & 63, wid = threadIdx.x >> 6;
    const int v = (i < n) ? deg[i] : 0;
    int inc = v;
    #pragma unroll
    for (int off = 1; off < 64; off <<= 1) {
        int u = __shfl_up(inc, off, 64);
        if (lane >= off) inc += u;
    }
    __shared__ int wsum[4];
    if (lane == 63) wsum[wid] = inc;
    __syncthreads();
    int woff = 0;
    for (int w = 0; w < wid; ++w) woff += wsum[w];
    if (i < n) {
        const int excl = bsum[blockIdx.x] + woff + inc - v;
        rowptr[i] = excl;
        cursor[i] = excl;
        norm[i] = rsqrtf((float)(v + 1));      // +1 self-loop
    }
}

// XCD-bucketed CSR fill; edge-list reads non-temporal (keep csr/cursor in L2).
__global__ __launch_bounds__(256) void fill_csr_x(const int* __restrict__ ei, int E,
                                                  int nper,
                                                  int* __restrict__ cursor,
                                                  int* __restrict__ csr_src) {
    const int r = blockIdx.x & 7;
    const int e = (blockIdx.x >> 3) * 256 + threadIdx.x;
    if (e >= E) return;
    const int d = __builtin_nontemporal_load(&ei[E + e]);
    if ((unsigned)(d - r * nper) < (unsigned)nper) {
        const int s = __builtin_nontemporal_load(&ei[e]);
        const int slot = atomicAdd(&cursor[d], 1);
        csr_src[slot] = s;
    }
}

// Tiled fp32 GEMM, 64-col output, premultiplied epilogue:
//   H'[row, colOff + c] = norm[row] * (A[row,:] @ W[:,c])
template<int LDW, bool HALF_OUT>
__global__ __launch_bounds__(256) void gemm64(
    const float* __restrict__ A, const float* __restrict__ W,
    const float* __restrict__ norm,
    void* __restrict__ Hout, int ldh, int colOff, int nrows)
{
    __shared__ float Ast[64 * 128];   // [row][k], float4-slot XOR swizzle
    __shared__ float Bst[128 * 64];   // [k][col], natural

    const int tid = threadIdx.x;
    const int tx = tid & 15;
    const int ty = tid >> 4;
    const int row0 = blockIdx.x * 64;

    {   // stage A
        const int kq = tid & 31;
        const int r  = tid >> 5;
        #pragma unroll
        for (int p = 0; p < 8; ++p) {
            int rr = r + p * 8;
            int grow = row0 + rr;
            if (grow > nrows - 1) grow = nrows - 1;
            float4 v = *(const float4*)&A[(size_t)grow * K_DIM + kq * 4];
            *(float4*)&Ast[rr * 128 + 4 * (kq ^ (rr & 7))] = v;
        }
    }
    {   // stage B
        const int cq = tid & 15;
        const int kr = tid >> 4;
        #pragma unroll
        for (int p = 0; p < 8; ++p) {
            int k = kr + p * 16;
            *(float4*)&Bst[k * 64 + cq * 4] = *(const float4*)&W[(size_t)k * LDW + cq * 4];
        }
    }
    __syncthreads();

    float acc[4][4] = {};
    #pragma unroll 2
    for (int k0 = 0; k0 < 128; k0 += 4) {
        float4 b[4];
        #pragma unroll
        for (int kk = 0; kk < 4; ++kk)
            b[kk] = *(const float4*)&Bst[(k0 + kk) * 64 + tx * 4];
        #pragma unroll
        for (int i = 0; i < 4; ++i) {
            const int rr = ty * 4 + i;
            float4 a = *(const float4*)&Ast[rr * 128 + 4 * ((k0 >> 2) ^ (rr & 7))];
            #pragma unroll
            for (int j = 0; j < 4; ++j) {
                acc[i][j] = fmaf(a.x, ((const float*)&b[0])[j], acc[i][j]);
                acc[i][j] = fmaf(a.y, ((const float*)&b[1])[j], acc[i][j]);
                acc[i][j] = fmaf(a.z, ((const float*)&b[2])[j], acc[i][j]);
                acc[i][j] = fmaf(a.w, ((const float*)&b[3])[j], acc[i][j]);
            }
        }
    }

    #pragma unroll
    for (int i = 0; i < 4; ++i) {
        int row = row0 + ty * 4 + i;
        if (row < nrows) {
            const float nr = norm[row];
            if (HALF_OUT) {
                __half2* hp = (__half2*)Hout + ((size_t)row * ldh + colOff + tx * 4) / 2;
                hp[0] = __floats2half2_rn(acc[i][0] * nr, acc[i][1] * nr);
                hp[1] = __floats2half2_rn(acc[i][2] * nr, acc[i][3] * nr);
            } else {
                float4 o = make_float4(acc[i][0] * nr, acc[i][1] * nr,
                                       acc[i][2] * nr, acc[i][3] * nr);
                *(float4*)((float*)Hout + (size_t)row * ldh + colOff + tx * 4) = o;
            }
        }
    }
}

// Layer-1 aggregation, ONE pass over 128 fp16 cols (lane owns cols 2L,2L+1):
//   agg[d,:] = relu( nd * (sum_e h'[s_e,:] + h'[d,:]) + bias )
// h' premultiplied by norm[src]; 8-way independent loads in the inner loop.
__global__ __launch_bounds__(256) void gather_relu_f16(
    const int* __restrict__ rowptr, const int* __restrict__ csr_src,
    const float* __restrict__ norm, const __half* __restrict__ h,
    const float* __restrict__ bias, float* __restrict__ agg, int n)
{
    const int lane = threadIdx.x & 63;
    const int w = threadIdx.x >> 6;
    const int d = blockIdx.x * 4 + w;
    if (d >= n) return;
    const __half2* hp = (const __half2*)h;   // row stride 64 half2

    float ax[8] = {}, ay[8] = {};
    const int jb = rowptr[d], je = rowptr[d + 1];
    for (int j0 = jb; j0 < je; j0 += 64) {
        const int cnt = (je - j0 < 64) ? (je - j0) : 64;
        int sidx = 0;
        if (lane < cnt) sidx = csr_src[j0 + lane];
        int t = 0;
        for (; t + 7 < cnt; t += 8) {
            float2 v[8];
            #pragma unroll
            for (int q = 0; q < 8; ++q) {
                const int s = __shfl(sidx, t + q, 64);
                v[q] = __half22float2(hp[(size_t)s * 64 + lane]);
            }
            #pragma unroll
            for (int q = 0; q < 8; ++q) { ax[q] += v[q].x; ay[q] += v[q].y; }
        }
        for (; t < cnt; ++t) {
            const int s = __shfl(sidx, t, 64);
            const float2 v = __half22float2(hp[(size_t)s * 64 + lane]);
            ax[0] += v.x; ay[0] += v.y;
        }
    }
    const float2 sv = __half22float2(hp[(size_t)d * 64 + lane]);   // self (premult)
    const float nd = norm[d];
    float sx = ((ax[0] + ax[1]) + (ax[2] + ax[3])) + ((ax[4] + ax[5]) + (ax[6] + ax[7])) + sv.x;
    float sy = ((ay[0] + ay[1]) + (ay[2] + ay[3])) + ((ay[4] + ay[5]) + (ay[6] + ay[7])) + sv.y;
    float2 o;
    o.x = fmaxf(fmaf(nd, sx, bias[2 * lane]), 0.f);
    o.y = fmaxf(fmaf(nd, sy, bias[2 * lane + 1]), 0.f);
    ((float2*)agg)[(size_t)d * 64 + lane] = o;
}

// Layer-2 aggregation + row softmax; h' fp32 premultiplied, 64 cols = 64 lanes.
__global__ __launch_bounds__(256) void gather_softmax(
    const int* __restrict__ rowptr, const int* __restrict__ csr_src,
    const float* __restrict__ norm, const float* __restrict__ h,
    const float* __restrict__ bias, float* __restrict__ out, int n)
{
    const int lane = threadIdx.x & 63;
    const int w = threadIdx.x >> 6;
    const int d = blockIdx.x * 4 + w;
    if (d >= n) return;

    float acc[8] = {};
    const int jb = rowptr[d], je = rowptr[d + 1];
    for (int j0 = jb; j0 < je; j0 += 64) {
        const int cnt = (je - j0 < 64) ? (je - j0) : 64;
        int sidx = 0;
        if (lane < cnt) sidx = csr_src[j0 + lane];
        int t = 0;
        for (; t + 7 < cnt; t += 8) {
            float v[8];
            #pragma unroll
            for (int q = 0; q < 8; ++q) {
                const int s = __shfl(sidx, t + q, 64);
                v[q] = h[(size_t)s * 64 + lane];
            }
            #pragma unroll
            for (int q = 0; q < 8; ++q) acc[q] += v[q];
        }
        for (; t < cnt; ++t) {
            const int s = __shfl(sidx, t, 64);
            acc[0] += h[(size_t)s * 64 + lane];
        }
    }
    const float nd = norm[d];
    float tot = ((acc[0] + acc[1]) + (acc[2] + acc[3])) +
                ((acc[4] + acc[5]) + (acc[6] + acc[7])) + h[(size_t)d * 64 + lane];
    float a = fmaf(nd, tot, bias[lane]);
    float m = a;
    #pragma unroll
    for (int off = 32; off; off >>= 1) m = fmaxf(m, __shfl_xor(m, off, 64));
    float ex = expf(a - m);
    float ssum = ex;
    #pragma unroll
    for (int off = 32; off; off >>= 1) ssum += __shfl_xor(ssum, off, 64);
    out[(size_t)d * 64 + lane] = ex / ssum;
}

extern "C" void kernel_launch(void* const* d_in, const int* in_sizes, int n_in,
                              void* d_out, int out_size, void* d_ws, size_t ws_size,
                              hipStream_t stream) {
    const float* x  = (const float*)d_in[0];
    const int*   ei = (const int*)d_in[1];
    const float* W1 = (const float*)d_in[2];
    const float* b1 = (const float*)d_in[3];
    const float* W2 = (const float*)d_in[4];
    const float* b2 = (const float*)d_in[5];
    float* out = (float*)d_out;

    const int N = in_sizes[0] / K_DIM;     // 100000
    const int E = in_sizes[1] / 2;         // 1600000
    const int nper = (N + 7) / 8;          // dst range per XCD bucket

    // Workspace layout (peak ~85 MB)
    size_t o = 0;
    char* base = (char*)d_ws;
    auto alloc = [&](size_t elems) {       // elems in 4-byte units
        void* p = base + o;
        o += (elems * 4 + 1023) & ~(size_t)1023;
        return p;
    };
    const int nb_n = (N + 255) / 256;
    int*    deg    = (int*)   alloc(N);
    int*    rowptr = (int*)   alloc(N + 1);
    int*    cursor = (int*)   alloc(N);
    float*  norm   = (float*) alloc(N);
    int*    bsum   = (int*)   alloc(nb_n);
    int*    csr    = (int*)   alloc(E);
    void*   bufA   = alloc((size_t)N * 64);          // h1' fp16 [Nx128] == h2' fp32 [Nx64]
    float*  agg1   = (float*) alloc((size_t)N * 128);

    __half* h1h = (__half*)bufA;
    float*  h2f = (float*)bufA;

    const int nb_e8 = ((E + 255) / 256) * 8;   // x8 XCD range buckets
    const int nb_g = (N + 3) / 4;
    const int nb_m = (N + 63) / 64;

    zero_int<<<nb_n, 256, 0, stream>>>(deg, N);
    deg_count_x<<<nb_e8, 256, 0, stream>>>(ei + E, E, nper, deg);
    block_sums<<<nb_n, 256, 0, stream>>>(deg, N, bsum);
    scan_bsums<<<1, 1024, 0, stream>>>(bsum, nb_n, rowptr, N);
    scan_write<<<nb_n, 256, 0, stream>>>(deg, bsum, N, rowptr, cursor, norm);
    fill_csr_x<<<nb_e8, 256, 0, stream>>>(ei, E, nper, cursor, csr);

    // Layer 1: h1' = norm .* (x@W1), fp16 [N x 128], two 64-col passes
    gemm64<128, true><<<nb_m, 256, 0, stream>>>(x, W1,      norm, h1h, 128, 0,  N);
    gemm64<128, true><<<nb_m, 256, 0, stream>>>(x, W1 + 64, norm, h1h, 128, 64, N);
    // Single-pass aggregation over all 128 cols
    gather_relu_f16<<<nb_g, 256, 0, stream>>>(rowptr, csr, norm, h1h, b1, agg1, N);

    // Layer 2: h2' = norm .* (agg1@W2), fp32 [N x 64]
    gemm64<64, false><<<nb_m, 256, 0, stream>>>(agg1, W2, norm, h2f, 64, 0, N);
    gather_softmax<<<nb_g, 256, 0, stream>>>(rowptr, csr, norm, h2f, b2, out, N);
}

// Round 8
// 377.760 us; speedup vs baseline: 1.2224x; 1.2224x over previous
//
#include <hip/hip_runtime.h>
#include <hip/hip_bf16.h>
#include <hip/hip_fp16.h>

// GCN: out = softmax( GCNConv2( relu( GCNConv1(x) ) ) )
// GCNConv(x) = D^-1/2 (A+I) D^-1/2 (x W) + b
//
// Round 8: CSR build restructured. R5-R7 showed the one-shot random scatter
// (fill_csr) is stuck at ~70 MB of partial-line write-backs (~70 us); L2
// residency hints (XCD bucketing, nontemporal loads) failed to fix it.
// New build: two-level partition.
//   1. hist_buckets + 1-wave scan: exact counts for 49 buckets of 2048 nodes.
//   2. partition_edges: LDS-staged grouping -> COALESCED writes of packed
//      (d_local<<17 | src) records into per-bucket contiguous regions.
//   3. build_csr: 1 block per bucket; bucket edges (~131 KB) + csr segment
//      (~131 KB) live on ONE CU/XCD -> L2-resident, full-line write-backs.
//      Also yields deg/rowptr/norm locally, deleting the old deg_count +
//      3-kernel scan chain entirely.
// Requires N <= 2^17 (src packs in 17 bits) and N <= 64*2048 (bucket count).
// N = 100000 here.

#define K_DIM 128
#define PART_VE 16
#define PART_CHUNK 4096   // 256 threads * 16 edges

__global__ __launch_bounds__(64) void zero_small(int* p) {
    p[threadIdx.x] = 0;
}

// Per-bucket edge counts (bucket = dst >> 11).
__global__ __launch_bounds__(256) void hist_buckets(const int* __restrict__ dst, int E,
                                                    int* __restrict__ bucket_count) {
    __shared__ int h[64];
    const int t = threadIdx.x;
    if (t < 64) h[t] = 0;
    __syncthreads();
    const int e0 = blockIdx.x * PART_CHUNK;
    #pragma unroll
    for (int q = 0; q < PART_VE; ++q) {
        const int e = e0 + q * 256 + t;
        if (e < E) atomicAdd(&h[dst[e] >> 11], 1);
    }
    __syncthreads();
    if (t < 64 && h[t]) atomicAdd(&bucket_count[t], h[t]);
}

// Single-wave exclusive scan of the 64 bucket counts.
__global__ __launch_bounds__(64) void scan_buckets(const int* __restrict__ bucket_count,
                                                   int* __restrict__ bucket_base,
                                                   int* __restrict__ bucket_cursor,
                                                   int* __restrict__ rowptr, int N, int E) {
    const int t = threadIdx.x;
    const int v = bucket_count[t];
    int inc = v;
    #pragma unroll
    for (int off = 1; off < 64; off <<= 1) {
        int u = __shfl_up(inc, off, 64);
        if (t >= off) inc += u;
    }
    bucket_base[t] = inc - v;
    bucket_cursor[t] = inc - v;
    if (t == 63) bucket_base[64] = inc;    // == E
    if (t == 0) rowptr[N] = E;
}

// Partition edges into per-bucket contiguous regions with coalesced writes.
// Packed record: (d & 2047) << 17 | src.
__global__ __launch_bounds__(256) void partition_edges(
    const int* __restrict__ ei, int E,
    int* __restrict__ bucket_cursor, int* __restrict__ packed_out)
{
    __shared__ int stage[PART_CHUNK];
    __shared__ unsigned char bstage[PART_CHUNK];
    __shared__ int hist[64], lbase[64], gbase[64], lcur[64];
    const int t = threadIdx.x;
    const int e0 = blockIdx.x * PART_CHUNK;
    if (t < 64) hist[t] = 0;
    __syncthreads();

    int pk[PART_VE], bk[PART_VE];
    #pragma unroll
    for (int q = 0; q < PART_VE; ++q) {
        const int e = e0 + q * 256 + t;
        bk[q] = -1;
        if (e < E) {
            const int s = ei[e];
            const int d = ei[E + e];
            bk[q] = d >> 11;
            pk[q] = ((d & 2047) << 17) | s;
            atomicAdd(&hist[bk[q]], 1);
        }
    }
    __syncthreads();

    if (t < 64) {    // wave 0: scan block-local bucket counts, reserve global space
        const int v = hist[t];
        int inc = v;
        #pragma unroll
        for (int off = 1; off < 64; off <<= 1) {
            int u = __shfl_up(inc, off, 64);
            if (t >= off) inc += u;
        }
        lbase[t] = inc - v;
        lcur[t]  = inc - v;
        gbase[t] = v ? atomicAdd(&bucket_cursor[t], v) : 0;
    }
    __syncthreads();

    #pragma unroll
    for (int q = 0; q < PART_VE; ++q) {
        if (bk[q] >= 0) {
            const int p = atomicAdd(&lcur[bk[q]], 1);
            stage[p]  = pk[q];
            bstage[p] = (unsigned char)bk[q];
        }
    }
    __syncthreads();

    const int total = (E - e0 < PART_CHUNK) ? (E - e0) : PART_CHUNK;
    for (int i = t; i < total; i += 256) {
        const int b = bstage[i];
        packed_out[gbase[b] + (i - lbase[b])] = stage[i];
    }
}

// One block per bucket: local histogram -> local scan -> rowptr/norm ->
// LDS-cursor scatter into this bucket's contiguous csr segment.
__global__ __launch_bounds__(1024) void build_csr(
    const int* __restrict__ packed, const int* __restrict__ bucket_base,
    int N, int* __restrict__ rowptr, float* __restrict__ normv,
    int* __restrict__ csr)
{
    __shared__ int ldeg[2048];
    __shared__ int lrow[2048];
    __shared__ int wtot[16];
    const int b = blockIdx.x;
    const int node0 = b << 11;
    const int t = threadIdx.x;
    const int jb = bucket_base[b], je = bucket_base[b + 1];

    ldeg[t] = 0; ldeg[t + 1024] = 0;
    __syncthreads();
    for (int j = jb + t; j < je; j += 1024)
        atomicAdd(&ldeg[packed[j] >> 17], 1);
    __syncthreads();

    // exclusive scan of ldeg[0..2048) -> lrow (thread t owns elems 2t, 2t+1)
    const int lane = t & 63, wid = t >> 6;
    const int v0 = ldeg[2 * t], v1 = ldeg[2 * t + 1];
    const int tsum = v0 + v1;
    int inc = tsum;
    #pragma unroll
    for (int off = 1; off < 64; off <<= 1) {
        int u = __shfl_up(inc, off, 64);
        if (lane >= off) inc += u;
    }
    if (lane == 63) wtot[wid] = inc;
    __syncthreads();
    int woff = 0;
    for (int w = 0; w < wid; ++w) woff += wtot[w];
    const int excl = woff + inc - tsum;
    lrow[2 * t] = excl;
    lrow[2 * t + 1] = excl + v0;
    __syncthreads();

    // rowptr + norm for real nodes (ldeg intact, lrow = local exclusive)
    const int nloc = (N - node0 < 2048) ? (N - node0) : 2048;
    for (int i = t; i < nloc; i += 1024) {
        rowptr[node0 + i] = jb + lrow[i];
        normv[node0 + i] = rsqrtf((float)(ldeg[i] + 1));   // +1 self-loop
    }
    __syncthreads();

    // scatter: lrow doubles as local cursor; writes confined to segment [jb,je)
    for (int j = jb + t; j < je; j += 1024) {
        const int v = packed[j];
        const int slot = jb + atomicAdd(&lrow[v >> 17], 1);
        csr[slot] = v & 0x1FFFF;
    }
}

// Tiled fp32 GEMM, 64-col output, premultiplied epilogue:
//   H'[row, colOff + c] = norm[row] * (A[row,:] @ W[:,c])
template<int LDW, bool HALF_OUT>
__global__ __launch_bounds__(256) void gemm64(
    const float* __restrict__ A, const float* __restrict__ W,
    const float* __restrict__ norm,
    void* __restrict__ Hout, int ldh, int colOff, int nrows)
{
    __shared__ float Ast[64 * 128];   // [row][k], float4-slot XOR swizzle
    __shared__ float Bst[128 * 64];   // [k][col], natural

    const int tid = threadIdx.x;
    const int tx = tid & 15;
    const int ty = tid >> 4;
    const int row0 = blockIdx.x * 64;

    {   // stage A
        const int kq = tid & 31;
        const int r  = tid >> 5;
        #pragma unroll
        for (int p = 0; p < 8; ++p) {
            int rr = r + p * 8;
            int grow = row0 + rr;
            if (grow > nrows - 1) grow = nrows - 1;
            float4 v = *(const float4*)&A[(size_t)grow * K_DIM + kq * 4];
            *(float4*)&Ast[rr * 128 + 4 * (kq ^ (rr & 7))] = v;
        }
    }
    {   // stage B
        const int cq = tid & 15;
        const int kr = tid >> 4;
        #pragma unroll
        for (int p = 0; p < 8; ++p) {
            int k = kr + p * 16;
            *(float4*)&Bst[k * 64 + cq * 4] = *(const float4*)&W[(size_t)k * LDW + cq * 4];
        }
    }
    __syncthreads();

    float acc[4][4] = {};
    #pragma unroll 2
    for (int k0 = 0; k0 < 128; k0 += 4) {
        float4 b[4];
        #pragma unroll
        for (int kk = 0; kk < 4; ++kk)
            b[kk] = *(const float4*)&Bst[(k0 + kk) * 64 + tx * 4];
        #pragma unroll
        for (int i = 0; i < 4; ++i) {
            const int rr = ty * 4 + i;
            float4 a = *(const float4*)&Ast[rr * 128 + 4 * ((k0 >> 2) ^ (rr & 7))];
            #pragma unroll
            for (int j = 0; j < 4; ++j) {
                acc[i][j] = fmaf(a.x, ((const float*)&b[0])[j], acc[i][j]);
                acc[i][j] = fmaf(a.y, ((const float*)&b[1])[j], acc[i][j]);
                acc[i][j] = fmaf(a.z, ((const float*)&b[2])[j], acc[i][j]);
                acc[i][j] = fmaf(a.w, ((const float*)&b[3])[j], acc[i][j]);
            }
        }
    }

    #pragma unroll
    for (int i = 0; i < 4; ++i) {
        int row = row0 + ty * 4 + i;
        if (row < nrows) {
            const float nr = norm[row];
            if (HALF_OUT) {
                __half2* hp = (__half2*)Hout + ((size_t)row * ldh + colOff + tx * 4) / 2;
                hp[0] = __floats2half2_rn(acc[i][0] * nr, acc[i][1] * nr);
                hp[1] = __floats2half2_rn(acc[i][2] * nr, acc[i][3] * nr);
            } else {
                float4 o = make_float4(acc[i][0] * nr, acc[i][1] * nr,
                                       acc[i][2] * nr, acc[i][3] * nr);
                *(float4*)((float*)Hout + (size_t)row * ldh + colOff + tx * 4) = o;
            }
        }
    }
}

// Layer-1 aggregation, ONE pass over 128 fp16 cols (lane owns cols 2L,2L+1):
//   agg[d,:] = relu( nd * (sum_e h'[s_e,:] + h'[d,:]) + bias )
__global__ __launch_bounds__(256) void gather_relu_f16(
    const int* __restrict__ rowptr, const int* __restrict__ csr_src,
    const float* __restrict__ norm, const __half* __restrict__ h,
    const float* __restrict__ bias, float* __restrict__ agg, int n)
{
    const int lane = threadIdx.x & 63;
    const int w = threadIdx.x >> 6;
    const int d = blockIdx.x * 4 + w;
    if (d >= n) return;
    const __half2* hp = (const __half2*)h;   // row stride 64 half2

    float ax[8] = {}, ay[8] = {};
    const int jb = rowptr[d], je = rowptr[d + 1];
    for (int j0 = jb; j0 < je; j0 += 64) {
        const int cnt = (je - j0 < 64) ? (je - j0) : 64;
        int sidx = 0;
        if (lane < cnt) sidx = csr_src[j0 + lane];
        int t = 0;
        for (; t + 7 < cnt; t += 8) {
            float2 v[8];
            #pragma unroll
            for (int q = 0; q < 8; ++q) {
                const int s = __shfl(sidx, t + q, 64);
                v[q] = __half22float2(hp[(size_t)s * 64 + lane]);
            }
            #pragma unroll
            for (int q = 0; q < 8; ++q) { ax[q] += v[q].x; ay[q] += v[q].y; }
        }
        for (; t < cnt; ++t) {
            const int s = __shfl(sidx, t, 64);
            const float2 v = __half22float2(hp[(size_t)s * 64 + lane]);
            ax[0] += v.x; ay[0] += v.y;
        }
    }
    const float2 sv = __half22float2(hp[(size_t)d * 64 + lane]);   // self (premult)
    const float nd = norm[d];
    float sx = ((ax[0] + ax[1]) + (ax[2] + ax[3])) + ((ax[4] + ax[5]) + (ax[6] + ax[7])) + sv.x;
    float sy = ((ay[0] + ay[1]) + (ay[2] + ay[3])) + ((ay[4] + ay[5]) + (ay[6] + ay[7])) + sv.y;
    float2 o;
    o.x = fmaxf(fmaf(nd, sx, bias[2 * lane]), 0.f);
    o.y = fmaxf(fmaf(nd, sy, bias[2 * lane + 1]), 0.f);
    ((float2*)agg)[(size_t)d * 64 + lane] = o;
}

// Layer-2 aggregation + row softmax; h' fp32 premultiplied, 64 cols = 64 lanes.
__global__ __launch_bounds__(256) void gather_softmax(
    const int* __restrict__ rowptr, const int* __restrict__ csr_src,
    const float* __restrict__ norm, const float* __restrict__ h,
    const float* __restrict__ bias, float* __restrict__ out, int n)
{
    const int lane = threadIdx.x & 63;
    const int w = threadIdx.x >> 6;
    const int d = blockIdx.x * 4 + w;
    if (d >= n) return;

    float acc[8] = {};
    const int jb = rowptr[d], je = rowptr[d + 1];
    for (int j0 = jb; j0 < je; j0 += 64) {
        const int cnt = (je - j0 < 64) ? (je - j0) : 64;
        int sidx = 0;
        if (lane < cnt) sidx = csr_src[j0 + lane];
        int t = 0;
        for (; t + 7 < cnt; t += 8) {
            float v[8];
            #pragma unroll
            for (int q = 0; q < 8; ++q) {
                const int s = __shfl(sidx, t + q, 64);
                v[q] = h[(size_t)s * 64 + lane];
            }
            #pragma unroll
            for (int q = 0; q < 8; ++q) acc[q] += v[q];
        }
        for (; t < cnt; ++t) {
            const int s = __shfl(sidx, t, 64);
            acc[0] += h[(size_t)s * 64 + lane];
        }
    }
    const float nd = norm[d];
    float tot = ((acc[0] + acc[1]) + (acc[2] + acc[3])) +
                ((acc[4] + acc[5]) + (acc[6] + acc[7])) + h[(size_t)d * 64 + lane];
    float a = fmaf(nd, tot, bias[lane]);
    float m = a;
    #pragma unroll
    for (int off = 32; off; off >>= 1) m = fmaxf(m, __shfl_xor(m, off, 64));
    float ex = expf(a - m);
    float ssum = ex;
    #pragma unroll
    for (int off = 32; off; off >>= 1) ssum += __shfl_xor(ssum, off, 64);
    out[(size_t)d * 64 + lane] = ex / ssum;
}

extern "C" void kernel_launch(void* const* d_in, const int* in_sizes, int n_in,
                              void* d_out, int out_size, void* d_ws, size_t ws_size,
                              hipStream_t stream) {
    const float* x  = (const float*)d_in[0];
    const int*   ei = (const int*)d_in[1];
    const float* W1 = (const float*)d_in[2];
    const float* b1 = (const float*)d_in[3];
    const float* W2 = (const float*)d_in[4];
    const float* b2 = (const float*)d_in[5];
    float* out = (float*)d_out;

    const int N = in_sizes[0] / K_DIM;     // 100000 (<= 2^17 required)
    const int E = in_sizes[1] / 2;         // 1600000
    const int NBUCK = (N + 2047) >> 11;    // 49 buckets of 2048 nodes

    // Workspace layout (peak ~91 MB)
    size_t o = 0;
    char* base = (char*)d_ws;
    auto alloc = [&](size_t elems) {       // elems in 4-byte units
        void* p = base + o;
        o += (elems * 4 + 1023) & ~(size_t)1023;
        return p;
    };
    int*    bcount = (int*)   alloc(64);
    int*    bbase  = (int*)   alloc(65);
    int*    bcur   = (int*)   alloc(64);
    int*    rowptr = (int*)   alloc(N + 1);
    float*  norm   = (float*) alloc(N);
    int*    packed = (int*)   alloc(E);
    int*    csr    = (int*)   alloc(E);
    void*   bufA   = alloc((size_t)N * 64);          // h1' fp16 [Nx128] == h2' fp32 [Nx64]
    float*  agg1   = (float*) alloc((size_t)N * 128);

    __half* h1h = (__half*)bufA;
    float*  h2f = (float*)bufA;

    const int nb_c = (E + PART_CHUNK - 1) / PART_CHUNK;   // partition chunks
    const int nb_g = (N + 3) / 4;
    const int nb_m = (N + 63) / 64;

    // ---- CSR build (two-level partition) ----
    zero_small<<<1, 64, 0, stream>>>(bcount);
    hist_buckets<<<nb_c, 256, 0, stream>>>(ei + E, E, bcount);
    scan_buckets<<<1, 64, 0, stream>>>(bcount, bbase, bcur, rowptr, N, E);
    partition_edges<<<nb_c, 256, 0, stream>>>(ei, E, bcur, packed);
    build_csr<<<NBUCK, 1024, 0, stream>>>(packed, bbase, N, rowptr, norm, csr);

    // ---- Layer 1: h1' = norm .* (x@W1), fp16 [N x 128], two 64-col passes ----
    gemm64<128, true><<<nb_m, 256, 0, stream>>>(x, W1,      norm, h1h, 128, 0,  N);
    gemm64<128, true><<<nb_m, 256, 0, stream>>>(x, W1 + 64, norm, h1h, 128, 64, N);
    gather_relu_f16<<<nb_g, 256, 0, stream>>>(rowptr, csr, norm, h1h, b1, agg1, N);

    // ---- Layer 2: h2' = norm .* (agg1@W2), fp32 [N x 64] ----
    gemm64<64, false><<<nb_m, 256, 0, stream>>>(agg1, W2, norm, h2f, 64, 0, N);
    gather_softmax<<<nb_g, 256, 0, stream>>>(rowptr, csr, norm, h2f, b2, out, N);
}

// Round 9
// 361.515 us; speedup vs baseline: 1.2774x; 1.0449x over previous
//
#include <hip/hip_runtime.h>
#include <hip/hip_bf16.h>
#include <hip/hip_fp16.h>

// GCN: out = softmax( GCNConv2( relu( GCNConv1(x) ) ) )
// GCNConv(x) = D^-1/2 (A+I) D^-1/2 (x W) + b
//
// Round 9:
//  (a) h2' stored fp16 [Nx64] (was fp32): layer-2 gather row 256B -> 128B,
//      logical traffic 410 -> 205 MB, working set 25.6 -> 12.8 MB (better L2
//      hit). R8 counters: gather_softmax FETCH 190 MB @ ~2.8 TB/s was the top
//      dispatch; row bytes drive it (the fp16 layer-1 gather ran faster on
//      identical edge count).
//  (b) CSR-build buckets 2048 -> 1024 nodes (49 -> 98 blocks): build_csr was
//      using only 49 of 256 CUs.
// Requires N <= 2^17 (src packs in 17 bits). N = 100000 here.

#define K_DIM 128
#define PART_VE 16
#define PART_CHUNK 4096   // 256 threads * 16 edges
#define NB_MAX 128        // bucket array size (N <= 128*1024)

__global__ __launch_bounds__(128) void zero_small(int* p) {
    p[threadIdx.x] = 0;
}

// Per-bucket edge counts (bucket = dst >> 10).
__global__ __launch_bounds__(256) void hist_buckets(const int* __restrict__ dst, int E,
                                                    int* __restrict__ bucket_count) {
    __shared__ int h[NB_MAX];
    const int t = threadIdx.x;
    if (t < NB_MAX) h[t] = 0;
    __syncthreads();
    const int e0 = blockIdx.x * PART_CHUNK;
    #pragma unroll
    for (int q = 0; q < PART_VE; ++q) {
        const int e = e0 + q * 256 + t;
        if (e < E) atomicAdd(&h[dst[e] >> 10], 1);
    }
    __syncthreads();
    if (t < NB_MAX && h[t]) atomicAdd(&bucket_count[t], h[t]);
}

// Single-wave exclusive scan of the 128 bucket counts (lane owns 2 buckets).
__global__ __launch_bounds__(64) void scan_buckets(const int* __restrict__ bucket_count,
                                                   int* __restrict__ bucket_base,
                                                   int* __restrict__ bucket_cursor,
                                                   int* __restrict__ rowptr, int N, int E) {
    const int t = threadIdx.x;
    const int v0 = bucket_count[2 * t], v1 = bucket_count[2 * t + 1];
    const int tsum = v0 + v1;
    int inc = tsum;
    #pragma unroll
    for (int off = 1; off < 64; off <<= 1) {
        int u = __shfl_up(inc, off, 64);
        if (t >= off) inc += u;
    }
    const int excl = inc - tsum;
    bucket_base[2 * t] = excl;
    bucket_base[2 * t + 1] = excl + v0;
    bucket_cursor[2 * t] = excl;
    bucket_cursor[2 * t + 1] = excl + v0;
    if (t == 63) bucket_base[NB_MAX] = inc;   // == E
    if (t == 0) rowptr[N] = E;
}

// Partition edges into per-bucket contiguous regions with coalesced writes.
// Packed record: (d & 1023) << 17 | src.
__global__ __launch_bounds__(256) void partition_edges(
    const int* __restrict__ ei, int E,
    int* __restrict__ bucket_cursor, int* __restrict__ packed_out)
{
    __shared__ int stage[PART_CHUNK];
    __shared__ unsigned char bstage[PART_CHUNK];
    __shared__ int hist[NB_MAX], lbase[NB_MAX], gbase[NB_MAX], lcur[NB_MAX];
    const int t = threadIdx.x;
    const int e0 = blockIdx.x * PART_CHUNK;
    if (t < NB_MAX) hist[t] = 0;
    __syncthreads();

    int pk[PART_VE], bk[PART_VE];
    #pragma unroll
    for (int q = 0; q < PART_VE; ++q) {
        const int e = e0 + q * 256 + t;
        bk[q] = -1;
        if (e < E) {
            const int s = ei[e];
            const int d = ei[E + e];
            bk[q] = d >> 10;
            pk[q] = ((d & 1023) << 17) | s;
            atomicAdd(&hist[bk[q]], 1);
        }
    }
    __syncthreads();

    if (t < 64) {   // wave 0: scan 128 block-local counts (2/lane), reserve space
        const int v0 = hist[2 * t], v1 = hist[2 * t + 1];
        const int tsum = v0 + v1;
        int inc = tsum;
        #pragma unroll
        for (int off = 1; off < 64; off <<= 1) {
            int u = __shfl_up(inc, off, 64);
            if (t >= off) inc += u;
        }
        const int excl = inc - tsum;
        lbase[2 * t] = excl;        lbase[2 * t + 1] = excl + v0;
        lcur[2 * t]  = excl;        lcur[2 * t + 1]  = excl + v0;
        gbase[2 * t]     = v0 ? atomicAdd(&bucket_cursor[2 * t], v0) : 0;
        gbase[2 * t + 1] = v1 ? atomicAdd(&bucket_cursor[2 * t + 1], v1) : 0;
    }
    __syncthreads();

    #pragma unroll
    for (int q = 0; q < PART_VE; ++q) {
        if (bk[q] >= 0) {
            const int p = atomicAdd(&lcur[bk[q]], 1);
            stage[p]  = pk[q];
            bstage[p] = (unsigned char)bk[q];
        }
    }
    __syncthreads();

    const int total = (E - e0 < PART_CHUNK) ? (E - e0) : PART_CHUNK;
    for (int i = t; i < total; i += 256) {
        const int b = bstage[i];
        packed_out[gbase[b] + (i - lbase[b])] = stage[i];
    }
}

// One block per 1024-node bucket: local histogram -> local scan -> rowptr/norm
// -> LDS-cursor scatter into this bucket's contiguous csr segment.
__global__ __launch_bounds__(1024) void build_csr(
    const int* __restrict__ packed, const int* __restrict__ bucket_base,
    int N, int* __restrict__ rowptr, float* __restrict__ normv,
    int* __restrict__ csr)
{
    __shared__ int ldeg[1024];
    __shared__ int lrow[1024];
    __shared__ int wtot[16];
    const int b = blockIdx.x;
    const int node0 = b << 10;
    const int t = threadIdx.x;
    const int jb = bucket_base[b], je = bucket_base[b + 1];

    ldeg[t] = 0;
    __syncthreads();
    for (int j = jb + t; j < je; j += 1024)
        atomicAdd(&ldeg[packed[j] >> 17], 1);
    __syncthreads();

    // exclusive scan of ldeg[0..1024) -> lrow
    const int lane = t & 63, wid = t >> 6;
    const int v = ldeg[t];
    int inc = v;
    #pragma unroll
    for (int off = 1; off < 64; off <<= 1) {
        int u = __shfl_up(inc, off, 64);
        if (lane >= off) inc += u;
    }
    if (lane == 63) wtot[wid] = inc;
    __syncthreads();
    int woff = 0;
    for (int w = 0; w < wid; ++w) woff += wtot[w];
    const int excl = woff + inc - v;
    lrow[t] = excl;
    __syncthreads();

    const int nloc = (N - node0 < 1024) ? (N - node0) : 1024;
    if (t < nloc) {
        rowptr[node0 + t] = jb + excl;
        normv[node0 + t] = rsqrtf((float)(v + 1));   // +1 self-loop
    }
    __syncthreads();

    // scatter: lrow doubles as local cursor; writes confined to [jb,je)
    for (int j = jb + t; j < je; j += 1024) {
        const int pv = packed[j];
        const int slot = jb + atomicAdd(&lrow[pv >> 17], 1);
        csr[slot] = pv & 0x1FFFF;
    }
}

// Tiled fp32 GEMM, 64-col output, premultiplied epilogue:
//   H'[row, colOff + c] = norm[row] * (A[row,:] @ W[:,c])
template<int LDW, bool HALF_OUT>
__global__ __launch_bounds__(256) void gemm64(
    const float* __restrict__ A, const float* __restrict__ W,
    const float* __restrict__ norm,
    void* __restrict__ Hout, int ldh, int colOff, int nrows)
{
    __shared__ float Ast[64 * 128];   // [row][k], float4-slot XOR swizzle
    __shared__ float Bst[128 * 64];   // [k][col], natural

    const int tid = threadIdx.x;
    const int tx = tid & 15;
    const int ty = tid >> 4;
    const int row0 = blockIdx.x * 64;

    {   // stage A
        const int kq = tid & 31;
        const int r  = tid >> 5;
        #pragma unroll
        for (int p = 0; p < 8; ++p) {
            int rr = r + p * 8;
            int grow = row0 + rr;
            if (grow > nrows - 1) grow = nrows - 1;
            float4 v = *(const float4*)&A[(size_t)grow * K_DIM + kq * 4];
            *(float4*)&Ast[rr * 128 + 4 * (kq ^ (rr & 7))] = v;
        }
    }
    {   // stage B
        const int cq = tid & 15;
        const int kr = tid >> 4;
        #pragma unroll
        for (int p = 0; p < 8; ++p) {
            int k = kr + p * 16;
            *(float4*)&Bst[k * 64 + cq * 4] = *(const float4*)&W[(size_t)k * LDW + cq * 4];
        }
    }
    __syncthreads();

    float acc[4][4] = {};
    #pragma unroll 2
    for (int k0 = 0; k0 < 128; k0 += 4) {
        float4 b[4];
        #pragma unroll
        for (int kk = 0; kk < 4; ++kk)
            b[kk] = *(const float4*)&Bst[(k0 + kk) * 64 + tx * 4];
        #pragma unroll
        for (int i = 0; i < 4; ++i) {
            const int rr = ty * 4 + i;
            float4 a = *(const float4*)&Ast[rr * 128 + 4 * ((k0 >> 2) ^ (rr & 7))];
            #pragma unroll
            for (int j = 0; j < 4; ++j) {
                acc[i][j] = fmaf(a.x, ((const float*)&b[0])[j], acc[i][j]);
                acc[i][j] = fmaf(a.y, ((const float*)&b[1])[j], acc[i][j]);
                acc[i][j] = fmaf(a.z, ((const float*)&b[2])[j], acc[i][j]);
                acc[i][j] = fmaf(a.w, ((const float*)&b[3])[j], acc[i][j]);
            }
        }
    }

    #pragma unroll
    for (int i = 0; i < 4; ++i) {
        int row = row0 + ty * 4 + i;
        if (row < nrows) {
            const float nr = norm[row];
            if (HALF_OUT) {
                __half2* hp = (__half2*)Hout + ((size_t)row * ldh + colOff + tx * 4) / 2;
                hp[0] = __floats2half2_rn(acc[i][0] * nr, acc[i][1] * nr);
                hp[1] = __floats2half2_rn(acc[i][2] * nr, acc[i][3] * nr);
            } else {
                float4 o = make_float4(acc[i][0] * nr, acc[i][1] * nr,
                                       acc[i][2] * nr, acc[i][3] * nr);
                *(float4*)((float*)Hout + (size_t)row * ldh + colOff + tx * 4) = o;
            }
        }
    }
}

// Layer-1 aggregation, ONE pass over 128 fp16 cols (lane owns cols 2L,2L+1):
//   agg[d,:] = relu( nd * (sum_e h'[s_e,:] + h'[d,:]) + bias )
__global__ __launch_bounds__(256) void gather_relu_f16(
    const int* __restrict__ rowptr, const int* __restrict__ csr_src,
    const float* __restrict__ norm, const __half* __restrict__ h,
    const float* __restrict__ bias, float* __restrict__ agg, int n)
{
    const int lane = threadIdx.x & 63;
    const int w = threadIdx.x >> 6;
    const int d = blockIdx.x * 4 + w;
    if (d >= n) return;
    const __half2* hp = (const __half2*)h;   // row stride 64 half2

    float ax[8] = {}, ay[8] = {};
    const int jb = rowptr[d], je = rowptr[d + 1];
    for (int j0 = jb; j0 < je; j0 += 64) {
        const int cnt = (je - j0 < 64) ? (je - j0) : 64;
        int sidx = 0;
        if (lane < cnt) sidx = csr_src[j0 + lane];
        int t = 0;
        for (; t + 7 < cnt; t += 8) {
            float2 v[8];
            #pragma unroll
            for (int q = 0; q < 8; ++q) {
                const int s = __shfl(sidx, t + q, 64);
                v[q] = __half22float2(hp[(size_t)s * 64 + lane]);
            }
            #pragma unroll
            for (int q = 0; q < 8; ++q) { ax[q] += v[q].x; ay[q] += v[q].y; }
        }
        for (; t < cnt; ++t) {
            const int s = __shfl(sidx, t, 64);
            const float2 v = __half22float2(hp[(size_t)s * 64 + lane]);
            ax[0] += v.x; ay[0] += v.y;
        }
    }
    const float2 sv = __half22float2(hp[(size_t)d * 64 + lane]);   // self (premult)
    const float nd = norm[d];
    float sx = ((ax[0] + ax[1]) + (ax[2] + ax[3])) + ((ax[4] + ax[5]) + (ax[6] + ax[7])) + sv.x;
    float sy = ((ay[0] + ay[1]) + (ay[2] + ay[3])) + ((ay[4] + ay[5]) + (ay[6] + ay[7])) + sv.y;
    float2 o;
    o.x = fmaxf(fmaf(nd, sx, bias[2 * lane]), 0.f);
    o.y = fmaxf(fmaf(nd, sy, bias[2 * lane + 1]), 0.f);
    ((float2*)agg)[(size_t)d * 64 + lane] = o;
}

// Layer-2 aggregation + row softmax; h' fp16 premultiplied, 64 cols = 64 lanes.
__global__ __launch_bounds__(256) void gather_softmax(
    const int* __restrict__ rowptr, const int* __restrict__ csr_src,
    const float* __restrict__ norm, const __half* __restrict__ h,
    const float* __restrict__ bias, float* __restrict__ out, int n)
{
    const int lane = threadIdx.x & 63;
    const int w = threadIdx.x >> 6;
    const int d = blockIdx.x * 4 + w;
    if (d >= n) return;

    float acc[8] = {};
    const int jb = rowptr[d], je = rowptr[d + 1];
    for (int j0 = jb; j0 < je; j0 += 64) {
        const int cnt = (je - j0 < 64) ? (je - j0) : 64;
        int sidx = 0;
        if (lane < cnt) sidx = csr_src[j0 + lane];
        int t = 0;
        for (; t + 7 < cnt; t += 8) {
            float v[8];
            #pragma unroll
            for (int q = 0; q < 8; ++q) {
                const int s = __shfl(sidx, t + q, 64);
                v[q] = __half2float(h[(size_t)s * 64 + lane]);
            }
            #pragma unroll
            for (int q = 0; q < 8; ++q) acc[q] += v[q];
        }
        for (; t < cnt; ++t) {
            const int s = __shfl(sidx, t, 64);
            acc[0] += __half2float(h[(size_t)s * 64 + lane]);
        }
    }
    const float nd = norm[d];
    float tot = ((acc[0] + acc[1]) + (acc[2] + acc[3])) +
                ((acc[4] + acc[5]) + (acc[6] + acc[7])) +
                __half2float(h[(size_t)d * 64 + lane]);
    float a = fmaf(nd, tot, bias[lane]);
    float m = a;
    #pragma unroll
    for (int off = 32; off; off >>= 1) m = fmaxf(m, __shfl_xor(m, off, 64));
    float ex = expf(a - m);
    float ssum = ex;
    #pragma unroll
    for (int off = 32; off; off >>= 1) ssum += __shfl_xor(ssum, off, 64);
    out[(size_t)d * 64 + lane] = ex / ssum;
}

extern "C" void kernel_launch(void* const* d_in, const int* in_sizes, int n_in,
                              void* d_out, int out_size, void* d_ws, size_t ws_size,
                              hipStream_t stream) {
    const float* x  = (const float*)d_in[0];
    const int*   ei = (const int*)d_in[1];
    const float* W1 = (const float*)d_in[2];
    const float* b1 = (const float*)d_in[3];
    const float* W2 = (const float*)d_in[4];
    const float* b2 = (const float*)d_in[5];
    float* out = (float*)d_out;

    const int N = in_sizes[0] / K_DIM;     // 100000 (<= 2^17 required)
    const int E = in_sizes[1] / 2;         // 1600000
    const int NBUCK = (N + 1023) >> 10;    // 98 buckets of 1024 nodes

    // Workspace layout (peak ~91 MB)
    size_t o = 0;
    char* base = (char*)d_ws;
    auto alloc = [&](size_t elems) {       // elems in 4-byte units
        void* p = base + o;
        o += (elems * 4 + 1023) & ~(size_t)1023;
        return p;
    };
    int*    bcount = (int*)   alloc(NB_MAX);
    int*    bbase  = (int*)   alloc(NB_MAX + 1);
    int*    bcur   = (int*)   alloc(NB_MAX);
    int*    rowptr = (int*)   alloc(N + 1);
    float*  norm   = (float*) alloc(N);
    int*    packed = (int*)   alloc(E);
    int*    csr    = (int*)   alloc(E);
    void*   bufA   = alloc((size_t)N * 64);          // h1' fp16 [Nx128] / h2' fp16 [Nx64]
    float*  agg1   = (float*) alloc((size_t)N * 128);

    __half* h1h = (__half*)bufA;
    __half* h2h = (__half*)bufA;

    const int nb_c = (E + PART_CHUNK - 1) / PART_CHUNK;   // partition chunks
    const int nb_g = (N + 3) / 4;
    const int nb_m = (N + 63) / 64;

    // ---- CSR build (two-level partition) ----
    zero_small<<<1, NB_MAX, 0, stream>>>(bcount);
    hist_buckets<<<nb_c, 256, 0, stream>>>(ei + E, E, bcount);
    scan_buckets<<<1, 64, 0, stream>>>(bcount, bbase, bcur, rowptr, N, E);
    partition_edges<<<nb_c, 256, 0, stream>>>(ei, E, bcur, packed);
    build_csr<<<NBUCK, 1024, 0, stream>>>(packed, bbase, N, rowptr, norm, csr);

    // ---- Layer 1: h1' = norm .* (x@W1), fp16 [N x 128], two 64-col passes ----
    gemm64<128, true><<<nb_m, 256, 0, stream>>>(x, W1,      norm, h1h, 128, 0,  N);
    gemm64<128, true><<<nb_m, 256, 0, stream>>>(x, W1 + 64, norm, h1h, 128, 64, N);
    gather_relu_f16<<<nb_g, 256, 0, stream>>>(rowptr, csr, norm, h1h, b1, agg1, N);

    // ---- Layer 2: h2' = norm .* (agg1@W2), fp16 [N x 64] ----
    gemm64<64, true><<<nb_m, 256, 0, stream>>>(agg1, W2, norm, h2h, 64, 0, N);
    gather_softmax<<<nb_g, 256, 0, stream>>>(rowptr, csr, norm, h2h, b2, out, N);
}

// Round 10
// 346.901 us; speedup vs baseline: 1.3312x; 1.0421x over previous
//
#include <hip/hip_runtime.h>
#include <hip/hip_bf16.h>
#include <hip/hip_fp16.h>

// GCN: out = softmax( GCNConv2( relu( GCNConv1(x) ) ) )
// GCNConv(x) = D^-1/2 (A+I) D^-1/2 (x W) + b
//
// Round 10:
//  (a) Scalar-path gathers: d made wave-uniform via readfirstlane so the edge
//      loop is a uniform scalar loop -> csr[j] via s_load (scalar cache) and
//      row loads as global_load v,[lane],s[base] (no per-edge VALU address
//      math, no shfl, no masking). R9: VALUBusy 48% in gather_relu_f16.
//      8-ahead scalar index prefetch keeps 8 row-loads in flight.
//  (b) Fused layer-1 GEMM (gemm128): 64x128 tile, B staged per 64-k half
//      (LDS = 64 KB exactly). Reads x ONCE (was twice), one dispatch fewer,
//      FMA:ds_read ratio 8 -> 10.7.
// Requires N <= 2^17 (src packs in 17 bits). N = 100000 here.

#define K_DIM 128
#define PART_VE 16
#define PART_CHUNK 4096   // 256 threads * 16 edges
#define NB_MAX 128        // bucket array size (N <= 128*1024)

__global__ __launch_bounds__(128) void zero_small(int* p) {
    p[threadIdx.x] = 0;
}

// Per-bucket edge counts (bucket = dst >> 10).
__global__ __launch_bounds__(256) void hist_buckets(const int* __restrict__ dst, int E,
                                                    int* __restrict__ bucket_count) {
    __shared__ int h[NB_MAX];
    const int t = threadIdx.x;
    if (t < NB_MAX) h[t] = 0;
    __syncthreads();
    const int e0 = blockIdx.x * PART_CHUNK;
    #pragma unroll
    for (int q = 0; q < PART_VE; ++q) {
        const int e = e0 + q * 256 + t;
        if (e < E) atomicAdd(&h[dst[e] >> 10], 1);
    }
    __syncthreads();
    if (t < NB_MAX && h[t]) atomicAdd(&bucket_count[t], h[t]);
}

// Single-wave exclusive scan of the 128 bucket counts (lane owns 2 buckets).
__global__ __launch_bounds__(64) void scan_buckets(const int* __restrict__ bucket_count,
                                                   int* __restrict__ bucket_base,
                                                   int* __restrict__ bucket_cursor,
                                                   int* __restrict__ rowptr, int N, int E) {
    const int t = threadIdx.x;
    const int v0 = bucket_count[2 * t], v1 = bucket_count[2 * t + 1];
    const int tsum = v0 + v1;
    int inc = tsum;
    #pragma unroll
    for (int off = 1; off < 64; off <<= 1) {
        int u = __shfl_up(inc, off, 64);
        if (t >= off) inc += u;
    }
    const int excl = inc - tsum;
    bucket_base[2 * t] = excl;
    bucket_base[2 * t + 1] = excl + v0;
    bucket_cursor[2 * t] = excl;
    bucket_cursor[2 * t + 1] = excl + v0;
    if (t == 63) bucket_base[NB_MAX] = inc;   // == E
    if (t == 0) rowptr[N] = E;
}

// Partition edges into per-bucket contiguous regions with coalesced writes.
// Packed record: (d & 1023) << 17 | src.
__global__ __launch_bounds__(256) void partition_edges(
    const int* __restrict__ ei, int E,
    int* __restrict__ bucket_cursor, int* __restrict__ packed_out)
{
    __shared__ int stage[PART_CHUNK];
    __shared__ unsigned char bstage[PART_CHUNK];
    __shared__ int hist[NB_MAX], lbase[NB_MAX], gbase[NB_MAX], lcur[NB_MAX];
    const int t = threadIdx.x;
    const int e0 = blockIdx.x * PART_CHUNK;
    if (t < NB_MAX) hist[t] = 0;
    __syncthreads();

    int pk[PART_VE], bk[PART_VE];
    #pragma unroll
    for (int q = 0; q < PART_VE; ++q) {
        const int e = e0 + q * 256 + t;
        bk[q] = -1;
        if (e < E) {
            const int s = ei[e];
            const int d = ei[E + e];
            bk[q] = d >> 10;
            pk[q] = ((d & 1023) << 17) | s;
            atomicAdd(&hist[bk[q]], 1);
        }
    }
    __syncthreads();

    if (t < 64) {   // wave 0: scan 128 block-local counts (2/lane), reserve space
        const int v0 = hist[2 * t], v1 = hist[2 * t + 1];
        const int tsum = v0 + v1;
        int inc = tsum;
        #pragma unroll
        for (int off = 1; off < 64; off <<= 1) {
            int u = __shfl_up(inc, off, 64);
            if (t >= off) inc += u;
        }
        const int excl = inc - tsum;
        lbase[2 * t] = excl;        lbase[2 * t + 1] = excl + v0;
        lcur[2 * t]  = excl;        lcur[2 * t + 1]  = excl + v0;
        gbase[2 * t]     = v0 ? atomicAdd(&bucket_cursor[2 * t], v0) : 0;
        gbase[2 * t + 1] = v1 ? atomicAdd(&bucket_cursor[2 * t + 1], v1) : 0;
    }
    __syncthreads();

    #pragma unroll
    for (int q = 0; q < PART_VE; ++q) {
        if (bk[q] >= 0) {
            const int p = atomicAdd(&lcur[bk[q]], 1);
            stage[p]  = pk[q];
            bstage[p] = (unsigned char)bk[q];
        }
    }
    __syncthreads();

    const int total = (E - e0 < PART_CHUNK) ? (E - e0) : PART_CHUNK;
    for (int i = t; i < total; i += 256) {
        const int b = bstage[i];
        packed_out[gbase[b] + (i - lbase[b])] = stage[i];
    }
}

// One block per 1024-node bucket: local histogram -> local scan -> rowptr/norm
// -> LDS-cursor scatter into this bucket's contiguous csr segment.
__global__ __launch_bounds__(1024) void build_csr(
    const int* __restrict__ packed, const int* __restrict__ bucket_base,
    int N, int* __restrict__ rowptr, float* __restrict__ normv,
    int* __restrict__ csr)
{
    __shared__ int ldeg[1024];
    __shared__ int lrow[1024];
    __shared__ int wtot[16];
    const int b = blockIdx.x;
    const int node0 = b << 10;
    const int t = threadIdx.x;
    const int jb = bucket_base[b], je = bucket_base[b + 1];

    ldeg[t] = 0;
    __syncthreads();
    for (int j = jb + t; j < je; j += 1024)
        atomicAdd(&ldeg[packed[j] >> 17], 1);
    __syncthreads();

    const int lane = t & 63, wid = t >> 6;
    const int v = ldeg[t];
    int inc = v;
    #pragma unroll
    for (int off = 1; off < 64; off <<= 1) {
        int u = __shfl_up(inc, off, 64);
        if (lane >= off) inc += u;
    }
    if (lane == 63) wtot[wid] = inc;
    __syncthreads();
    int woff = 0;
    for (int w = 0; w < wid; ++w) woff += wtot[w];
    const int excl = woff + inc - v;
    lrow[t] = excl;
    __syncthreads();

    const int nloc = (N - node0 < 1024) ? (N - node0) : 1024;
    if (t < nloc) {
        rowptr[node0 + t] = jb + excl;
        normv[node0 + t] = rsqrtf((float)(v + 1));   // +1 self-loop
    }
    __syncthreads();

    for (int j = jb + t; j < je; j += 1024) {
        const int pv = packed[j];
        const int slot = jb + atomicAdd(&lrow[pv >> 17], 1);
        csr[slot] = pv & 0x1FFFF;
    }
}

// Fused layer-1 GEMM: H'[row,0..127] = norm[row] * (A[row,:] @ W[:,0..127]),
// fp16 output. 64-row x 128-col tile; B staged per 64-k half (LDS 64 KB).
__global__ __launch_bounds__(256) void gemm128(
    const float* __restrict__ A, const float* __restrict__ W,
    const float* __restrict__ norm, __half* __restrict__ Hout, int nrows)
{
    __shared__ float Ast[64 * 128];   // [row][k], float4-slot XOR swizzle (32 KB)
    __shared__ float Bst[64 * 128];   // [k-in-half][col], natural (32 KB)

    const int tid = threadIdx.x;
    const int tx = tid & 15;
    const int ty = tid >> 4;
    const int row0 = blockIdx.x * 64;

    {   // stage A once
        const int kq = tid & 31;
        const int r  = tid >> 5;
        #pragma unroll
        for (int p = 0; p < 8; ++p) {
            int rr = r + p * 8;
            int grow = row0 + rr;
            if (grow > nrows - 1) grow = nrows - 1;
            float4 v = *(const float4*)&A[(size_t)grow * K_DIM + kq * 4];
            *(float4*)&Ast[rr * 128 + 4 * (kq ^ (rr & 7))] = v;
        }
    }

    float acc[4][8] = {};   // 4 rows x (cols tx*4..+3 and 64+tx*4..+3)
    #pragma unroll
    for (int half = 0; half < 2; ++half) {
        if (half) __syncthreads();   // protect Bst before restage
        {   // stage B half: rows half*64..+63 of W, all 128 cols
            const int cq = tid & 31;
            const int kr = tid >> 5;
            #pragma unroll
            for (int p = 0; p < 8; ++p) {
                int k = kr + p * 8;
                *(float4*)&Bst[k * 128 + cq * 4] =
                    *(const float4*)&W[(size_t)(half * 64 + k) * 128 + cq * 4];
            }
        }
        __syncthreads();

        #pragma unroll 2
        for (int k0 = 0; k0 < 64; k0 += 4) {
            float4 b[4][2];
            #pragma unroll
            for (int kk = 0; kk < 4; ++kk) {
                b[kk][0] = *(const float4*)&Bst[(k0 + kk) * 128 + tx * 4];
                b[kk][1] = *(const float4*)&Bst[(k0 + kk) * 128 + 64 + tx * 4];
            }
            const int kq = (half * 64 + k0) >> 2;
            #pragma unroll
            for (int i = 0; i < 4; ++i) {
                const int rr = ty * 4 + i;
                float4 a = *(const float4*)&Ast[rr * 128 + 4 * (kq ^ (rr & 7))];
                #pragma unroll
                for (int g = 0; g < 2; ++g) {
                    #pragma unroll
                    for (int j = 0; j < 4; ++j) {
                        float* ac = &acc[i][g * 4 + j];
                        *ac = fmaf(a.x, ((const float*)&b[0][g])[j], *ac);
                        *ac = fmaf(a.y, ((const float*)&b[1][g])[j], *ac);
                        *ac = fmaf(a.z, ((const float*)&b[2][g])[j], *ac);
                        *ac = fmaf(a.w, ((const float*)&b[3][g])[j], *ac);
                    }
                }
            }
        }
    }

    #pragma unroll
    for (int i = 0; i < 4; ++i) {
        int row = row0 + ty * 4 + i;
        if (row < nrows) {
            const float nr = norm[row];
            __half2* hp = (__half2*)&Hout[(size_t)row * 128];
            hp[tx * 2]     = __floats2half2_rn(acc[i][0] * nr, acc[i][1] * nr);
            hp[tx * 2 + 1] = __floats2half2_rn(acc[i][2] * nr, acc[i][3] * nr);
            hp[32 + tx * 2]     = __floats2half2_rn(acc[i][4] * nr, acc[i][5] * nr);
            hp[32 + tx * 2 + 1] = __floats2half2_rn(acc[i][6] * nr, acc[i][7] * nr);
        }
    }
}

// Layer-2 GEMM: H'[row,0..63] = norm[row] * (A[row,:] @ W2), fp16 out.
__global__ __launch_bounds__(256) void gemm64(
    const float* __restrict__ A, const float* __restrict__ W,
    const float* __restrict__ norm, __half* __restrict__ Hout, int nrows)
{
    __shared__ float Ast[64 * 128];   // [row][k], swizzled
    __shared__ float Bst[128 * 64];   // [k][col], natural

    const int tid = threadIdx.x;
    const int tx = tid & 15;
    const int ty = tid >> 4;
    const int row0 = blockIdx.x * 64;

    {   // stage A
        const int kq = tid & 31;
        const int r  = tid >> 5;
        #pragma unroll
        for (int p = 0; p < 8; ++p) {
            int rr = r + p * 8;
            int grow = row0 + rr;
            if (grow > nrows - 1) grow = nrows - 1;
            float4 v = *(const float4*)&A[(size_t)grow * K_DIM + kq * 4];
            *(float4*)&Ast[rr * 128 + 4 * (kq ^ (rr & 7))] = v;
        }
    }
    {   // stage B
        const int cq = tid & 15;
        const int kr = tid >> 4;
        #pragma unroll
        for (int p = 0; p < 8; ++p) {
            int k = kr + p * 16;
            *(float4*)&Bst[k * 64 + cq * 4] = *(const float4*)&W[(size_t)k * 64 + cq * 4];
        }
    }
    __syncthreads();

    float acc[4][4] = {};
    #pragma unroll 2
    for (int k0 = 0; k0 < 128; k0 += 4) {
        float4 b[4];
        #pragma unroll
        for (int kk = 0; kk < 4; ++kk)
            b[kk] = *(const float4*)&Bst[(k0 + kk) * 64 + tx * 4];
        #pragma unroll
        for (int i = 0; i < 4; ++i) {
            const int rr = ty * 4 + i;
            float4 a = *(const float4*)&Ast[rr * 128 + 4 * ((k0 >> 2) ^ (rr & 7))];
            #pragma unroll
            for (int j = 0; j < 4; ++j) {
                acc[i][j] = fmaf(a.x, ((const float*)&b[0])[j], acc[i][j]);
                acc[i][j] = fmaf(a.y, ((const float*)&b[1])[j], acc[i][j]);
                acc[i][j] = fmaf(a.z, ((const float*)&b[2])[j], acc[i][j]);
                acc[i][j] = fmaf(a.w, ((const float*)&b[3])[j], acc[i][j]);
            }
        }
    }

    #pragma unroll
    for (int i = 0; i < 4; ++i) {
        int row = row0 + ty * 4 + i;
        if (row < nrows) {
            const float nr = norm[row];
            __half2* hp = (__half2*)&Hout[(size_t)row * 64];
            hp[tx * 2]     = __floats2half2_rn(acc[i][0] * nr, acc[i][1] * nr);
            hp[tx * 2 + 1] = __floats2half2_rn(acc[i][2] * nr, acc[i][3] * nr);
        }
    }
}

// Layer-1 aggregation (scalar-path): d wave-uniform; csr indices via scalar
// loads; lane owns cols 2L,2L+1 (one half2 per edge, zero VALU addr math).
//   agg[d,:] = relu( nd * (sum_e h'[s_e,:] + h'[d,:]) + bias )
__global__ __launch_bounds__(256) void gather_relu_f16(
    const int* __restrict__ rowptr, const int* __restrict__ csr,
    const float* __restrict__ norm, const __half* __restrict__ h,
    const float* __restrict__ bias, float* __restrict__ agg, int n)
{
    const int lane = threadIdx.x & 63;
    const int d = __builtin_amdgcn_readfirstlane(blockIdx.x * 4 + (threadIdx.x >> 6));
    if (d >= n) return;
    const __half2* hp = (const __half2*)h;   // row stride 64 half2 (256 B)

    const int jb = rowptr[d], je = rowptr[d + 1];
    float ax[8] = {}, ay[8] = {};
    int j = jb;
    if (j + 8 <= je) {
        int s[8];
        #pragma unroll
        for (int q = 0; q < 8; ++q) s[q] = csr[j + q];
        for (; j + 16 <= je; j += 8) {
            int sn[8];
            #pragma unroll
            for (int q = 0; q < 8; ++q) sn[q] = csr[j + 8 + q];
            #pragma unroll
            for (int q = 0; q < 8; ++q) {
                const float2 v = __half22float2(hp[(size_t)s[q] * 64 + lane]);
                ax[q] += v.x; ay[q] += v.y;
            }
            #pragma unroll
            for (int q = 0; q < 8; ++q) s[q] = sn[q];
        }
        #pragma unroll
        for (int q = 0; q < 8; ++q) {
            const float2 v = __half22float2(hp[(size_t)s[q] * 64 + lane]);
            ax[q] += v.x; ay[q] += v.y;
        }
        j += 8;
    }
    for (; j < je; ++j) {
        const float2 v = __half22float2(hp[(size_t)csr[j] * 64 + lane]);
        ax[0] += v.x; ay[0] += v.y;
    }

    const float2 sv = __half22float2(hp[(size_t)d * 64 + lane]);   // self (premult)
    const float nd = norm[d];
    float sx = ((ax[0] + ax[1]) + (ax[2] + ax[3])) + ((ax[4] + ax[5]) + (ax[6] + ax[7])) + sv.x;
    float sy = ((ay[0] + ay[1]) + (ay[2] + ay[3])) + ((ay[4] + ay[5]) + (ay[6] + ay[7])) + sv.y;
    float2 o;
    o.x = fmaxf(fmaf(nd, sx, bias[2 * lane]), 0.f);
    o.y = fmaxf(fmaf(nd, sy, bias[2 * lane + 1]), 0.f);
    ((float2*)agg)[(size_t)d * 64 + lane] = o;
}

// Layer-2 aggregation + row softmax (scalar-path); h' fp16, 64 cols = 64 lanes.
__global__ __launch_bounds__(256) void gather_softmax(
    const int* __restrict__ rowptr, const int* __restrict__ csr,
    const float* __restrict__ norm, const __half* __restrict__ h,
    const float* __restrict__ bias, float* __restrict__ out, int n)
{
    const int lane = threadIdx.x & 63;
    const int d = __builtin_amdgcn_readfirstlane(blockIdx.x * 4 + (threadIdx.x >> 6));
    if (d >= n) return;

    const int jb = rowptr[d], je = rowptr[d + 1];
    float acc[8] = {};
    int j = jb;
    if (j + 8 <= je) {
        int s[8];
        #pragma unroll
        for (int q = 0; q < 8; ++q) s[q] = csr[j + q];
        for (; j + 16 <= je; j += 8) {
            int sn[8];
            #pragma unroll
            for (int q = 0; q < 8; ++q) sn[q] = csr[j + 8 + q];
            #pragma unroll
            for (int q = 0; q < 8; ++q)
                acc[q] += __half2float(h[(size_t)s[q] * 64 + lane]);
            #pragma unroll
            for (int q = 0; q < 8; ++q) s[q] = sn[q];
        }
        #pragma unroll
        for (int q = 0; q < 8; ++q)
            acc[q] += __half2float(h[(size_t)s[q] * 64 + lane]);
        j += 8;
    }
    for (; j < je; ++j)
        acc[0] += __half2float(h[(size_t)csr[j] * 64 + lane]);

    const float nd = norm[d];
    float tot = ((acc[0] + acc[1]) + (acc[2] + acc[3])) +
                ((acc[4] + acc[5]) + (acc[6] + acc[7])) +
                __half2float(h[(size_t)d * 64 + lane]);
    float a = fmaf(nd, tot, bias[lane]);
    float m = a;
    #pragma unroll
    for (int off = 32; off; off >>= 1) m = fmaxf(m, __shfl_xor(m, off, 64));
    float ex = expf(a - m);
    float ssum = ex;
    #pragma unroll
    for (int off = 32; off; off >>= 1) ssum += __shfl_xor(ssum, off, 64);
    out[(size_t)d * 64 + lane] = ex / ssum;
}

extern "C" void kernel_launch(void* const* d_in, const int* in_sizes, int n_in,
                              void* d_out, int out_size, void* d_ws, size_t ws_size,
                              hipStream_t stream) {
    const float* x  = (const float*)d_in[0];
    const int*   ei = (const int*)d_in[1];
    const float* W1 = (const float*)d_in[2];
    const float* b1 = (const float*)d_in[3];
    const float* W2 = (const float*)d_in[4];
    const float* b2 = (const float*)d_in[5];
    float* out = (float*)d_out;

    const int N = in_sizes[0] / K_DIM;     // 100000 (<= 2^17 required)
    const int E = in_sizes[1] / 2;         // 1600000
    const int NBUCK = (N + 1023) >> 10;    // 98 buckets of 1024 nodes

    // Workspace layout (peak ~91 MB)
    size_t o = 0;
    char* base = (char*)d_ws;
    auto alloc = [&](size_t elems) {       // elems in 4-byte units
        void* p = base + o;
        o += (elems * 4 + 1023) & ~(size_t)1023;
        return p;
    };
    int*    bcount = (int*)   alloc(NB_MAX);
    int*    bbase  = (int*)   alloc(NB_MAX + 1);
    int*    bcur   = (int*)   alloc(NB_MAX);
    int*    rowptr = (int*)   alloc(N + 1);
    float*  norm   = (float*) alloc(N);
    int*    packed = (int*)   alloc(E);
    int*    csr    = (int*)   alloc(E);
    void*   bufA   = alloc((size_t)N * 64);          // h1' fp16 [Nx128] / h2' fp16 [Nx64]
    float*  agg1   = (float*) alloc((size_t)N * 128);

    __half* h1h = (__half*)bufA;
    __half* h2h = (__half*)bufA;

    const int nb_c = (E + PART_CHUNK - 1) / PART_CHUNK;   // partition chunks
    const int nb_g = (N + 3) / 4;
    const int nb_m = (N + 63) / 64;

    // ---- CSR build (two-level partition) ----
    zero_small<<<1, NB_MAX, 0, stream>>>(bcount);
    hist_buckets<<<nb_c, 256, 0, stream>>>(ei + E, E, bcount);
    scan_buckets<<<1, 64, 0, stream>>>(bcount, bbase, bcur, rowptr, N, E);
    partition_edges<<<nb_c, 256, 0, stream>>>(ei, E, bcur, packed);
    build_csr<<<NBUCK, 1024, 0, stream>>>(packed, bbase, N, rowptr, norm, csr);

    // ---- Layer 1: h1' = norm .* (x@W1), fp16 [N x 128], ONE fused pass ----
    gemm128<<<nb_m, 256, 0, stream>>>(x, W1, norm, h1h, N);
    gather_relu_f16<<<nb_g, 256, 0, stream>>>(rowptr, csr, norm, h1h, b1, agg1, N);

    // ---- Layer 2: h2' = norm .* (agg1@W2), fp16 [N x 64] ----
    gemm64<<<nb_m, 256, 0, stream>>>(agg1, W2, norm, h2h, N);
    gather_softmax<<<nb_g, 256, 0, stream>>>(rowptr, csr, norm, h2h, b2, out, N);
}

// Round 11
// 299.123 us; speedup vs baseline: 1.5438x; 1.1597x over previous
//
#include <hip/hip_runtime.h>
#include <hip/hip_bf16.h>
#include <hip/hip_fp16.h>

// GCN: out = softmax( GCNConv2( relu( GCNConv1(x) ) ) )
// GCNConv(x) = D^-1/2 (A+I) D^-1/2 (x W) + b
//
// Round 11:
//  (a) GEMMs moved to matrix cores (mfma_f32_16x16x32_f16). fp32 VALU GEMMs
//      were ~60+38 us at ~50 TF; MFMA is staging-bound ~15+10 us. Precision:
//      h'/agg are ALREADY fp16-quantized for the gathers; layer-1 uses
//      split-A (x=hi+lo, 2 MFMAs) so only W-fp16 error (~3e-4 rel) is added.
//      Fragment maps (m89-verified): A[m=lane&15][k=quad*8+j],
//      B[k=quad*8+j][n=lane&15], D[row=quad*4+reg][col=lane&15]. Weights
//      pre-transposed to [n][k] fp16 (prep_weights) so A and B fragments are
//      contiguous ds_read_b128; LDS rows padded +8 halfs (2-way alias=free).
//  (b) agg1 stored fp16: halves gather_relu write traffic and gemm64 fetch.
// Requires N <= 2^17. N = 100000 here.

#define K_DIM 128
#define PART_VE 16
#define PART_CHUNK 4096   // 256 threads * 16 edges
#define NB_MAX 128        // bucket array size (N <= 128*1024)
#define LDA 136           // LDS row stride in halfs (128 + 8 pad)

typedef _Float16 half8 __attribute__((ext_vector_type(8)));
typedef float floatx4 __attribute__((ext_vector_type(4)));

__global__ __launch_bounds__(128) void zero_small(int* p) {
    p[threadIdx.x] = 0;
}

// Per-bucket edge counts (bucket = dst >> 10).
__global__ __launch_bounds__(256) void hist_buckets(const int* __restrict__ dst, int E,
                                                    int* __restrict__ bucket_count) {
    __shared__ int h[NB_MAX];
    const int t = threadIdx.x;
    if (t < NB_MAX) h[t] = 0;
    __syncthreads();
    const int e0 = blockIdx.x * PART_CHUNK;
    #pragma unroll
    for (int q = 0; q < PART_VE; ++q) {
        const int e = e0 + q * 256 + t;
        if (e < E) atomicAdd(&h[dst[e] >> 10], 1);
    }
    __syncthreads();
    if (t < NB_MAX && h[t]) atomicAdd(&bucket_count[t], h[t]);
}

// Single-wave exclusive scan of the 128 bucket counts (lane owns 2 buckets).
__global__ __launch_bounds__(64) void scan_buckets(const int* __restrict__ bucket_count,
                                                   int* __restrict__ bucket_base,
                                                   int* __restrict__ bucket_cursor,
                                                   int* __restrict__ rowptr, int N, int E) {
    const int t = threadIdx.x;
    const int v0 = bucket_count[2 * t], v1 = bucket_count[2 * t + 1];
    const int tsum = v0 + v1;
    int inc = tsum;
    #pragma unroll
    for (int off = 1; off < 64; off <<= 1) {
        int u = __shfl_up(inc, off, 64);
        if (t >= off) inc += u;
    }
    const int excl = inc - tsum;
    bucket_base[2 * t] = excl;
    bucket_base[2 * t + 1] = excl + v0;
    bucket_cursor[2 * t] = excl;
    bucket_cursor[2 * t + 1] = excl + v0;
    if (t == 63) bucket_base[NB_MAX] = inc;   // == E
    if (t == 0) rowptr[N] = E;
}

// Partition edges into per-bucket contiguous regions with coalesced writes.
// Packed record: (d & 1023) << 17 | src.
__global__ __launch_bounds__(256) void partition_edges(
    const int* __restrict__ ei, int E,
    int* __restrict__ bucket_cursor, int* __restrict__ packed_out)
{
    __shared__ int stage[PART_CHUNK];
    __shared__ unsigned char bstage[PART_CHUNK];
    __shared__ int hist[NB_MAX], lbase[NB_MAX], gbase[NB_MAX], lcur[NB_MAX];
    const int t = threadIdx.x;
    const int e0 = blockIdx.x * PART_CHUNK;
    if (t < NB_MAX) hist[t] = 0;
    __syncthreads();

    int pk[PART_VE], bk[PART_VE];
    #pragma unroll
    for (int q = 0; q < PART_VE; ++q) {
        const int e = e0 + q * 256 + t;
        bk[q] = -1;
        if (e < E) {
            const int s = ei[e];
            const int d = ei[E + e];
            bk[q] = d >> 10;
            pk[q] = ((d & 1023) << 17) | s;
            atomicAdd(&hist[bk[q]], 1);
        }
    }
    __syncthreads();

    if (t < 64) {
        const int v0 = hist[2 * t], v1 = hist[2 * t + 1];
        const int tsum = v0 + v1;
        int inc = tsum;
        #pragma unroll
        for (int off = 1; off < 64; off <<= 1) {
            int u = __shfl_up(inc, off, 64);
            if (t >= off) inc += u;
        }
        const int excl = inc - tsum;
        lbase[2 * t] = excl;        lbase[2 * t + 1] = excl + v0;
        lcur[2 * t]  = excl;        lcur[2 * t + 1]  = excl + v0;
        gbase[2 * t]     = v0 ? atomicAdd(&bucket_cursor[2 * t], v0) : 0;
        gbase[2 * t + 1] = v1 ? atomicAdd(&bucket_cursor[2 * t + 1], v1) : 0;
    }
    __syncthreads();

    #pragma unroll
    for (int q = 0; q < PART_VE; ++q) {
        if (bk[q] >= 0) {
            const int p = atomicAdd(&lcur[bk[q]], 1);
            stage[p]  = pk[q];
            bstage[p] = (unsigned char)bk[q];
        }
    }
    __syncthreads();

    const int total = (E - e0 < PART_CHUNK) ? (E - e0) : PART_CHUNK;
    for (int i = t; i < total; i += 256) {
        const int b = bstage[i];
        packed_out[gbase[b] + (i - lbase[b])] = stage[i];
    }
}

// One block per 1024-node bucket: local histogram -> local scan -> rowptr/norm
// -> LDS-cursor scatter into this bucket's contiguous csr segment.
__global__ __launch_bounds__(1024) void build_csr(
    const int* __restrict__ packed, const int* __restrict__ bucket_base,
    int N, int* __restrict__ rowptr, float* __restrict__ normv,
    int* __restrict__ csr)
{
    __shared__ int ldeg[1024];
    __shared__ int lrow[1024];
    __shared__ int wtot[16];
    const int b = blockIdx.x;
    const int node0 = b << 10;
    const int t = threadIdx.x;
    const int jb = bucket_base[b], je = bucket_base[b + 1];

    ldeg[t] = 0;
    __syncthreads();
    for (int j = jb + t; j < je; j += 1024)
        atomicAdd(&ldeg[packed[j] >> 17], 1);
    __syncthreads();

    const int lane = t & 63, wid = t >> 6;
    const int v = ldeg[t];
    int inc = v;
    #pragma unroll
    for (int off = 1; off < 64; off <<= 1) {
        int u = __shfl_up(inc, off, 64);
        if (lane >= off) inc += u;
    }
    if (lane == 63) wtot[wid] = inc;
    __syncthreads();
    int woff = 0;
    for (int w = 0; w < wid; ++w) woff += wtot[w];
    const int excl = woff + inc - v;
    lrow[t] = excl;
    __syncthreads();

    const int nloc = (N - node0 < 1024) ? (N - node0) : 1024;
    if (t < nloc) {
        rowptr[node0 + t] = jb + excl;
        normv[node0 + t] = rsqrtf((float)(v + 1));   // +1 self-loop
    }
    __syncthreads();

    for (int j = jb + t; j < je; j += 1024) {
        const int pv = packed[j];
        const int slot = jb + atomicAdd(&lrow[pv >> 17], 1);
        csr[slot] = pv & 0x1FFFF;
    }
}

// Transpose-convert weights for MFMA B-operand: W1h[n][k] = (half)W1[k][n],
// W2h[n][k] = (half)W2[k][n]. 16384 + 8192 elems; one tiny kernel.
__global__ __launch_bounds__(256) void prep_weights(
    const float* __restrict__ W1, const float* __restrict__ W2,
    __half* __restrict__ W1h, __half* __restrict__ W2h)
{
    const int idx = blockIdx.x * 256 + threadIdx.x;
    if (idx < 128 * 128) {
        const int n = idx >> 7, k = idx & 127;
        W1h[idx] = __float2half(W1[k * 128 + n]);
    }
    const int idx2 = idx - 128 * 128;
    if (idx2 >= 0 && idx2 < 64 * 128) {
        const int n = idx2 >> 7, k = idx2 & 127;
        W2h[idx2] = __float2half(W2[k * 64 + n]);
    }
}

// Layer-1 MFMA GEMM: H'[row,0..127] = norm[row]*(x[row,:]@W1), fp16 out.
// Split-A (x = hi + lo) so only W-fp16 quantization enters the result.
// 256 thr = 4 waves; wave w owns rows w*16..+15, all 8 col-tiles.
__global__ __launch_bounds__(256) void gemm128_mfma(
    const float* __restrict__ A, const __half* __restrict__ Wh,  // [n][k]
    const float* __restrict__ norm, __half* __restrict__ Hout, int nrows)
{
    __shared__ _Float16 Ah[64 * LDA];
    __shared__ _Float16 Al[64 * LDA];
    __shared__ _Float16 Bh[128 * LDA];
    const int t = threadIdx.x;
    const int row0 = blockIdx.x * 64;

    {   // stage A split hi/lo: thread t -> row t>>2, 32-col segment (t&3)*32
        const int r = t >> 2;
        const int seg = (t & 3) * 32;
        int grow = row0 + r;
        if (grow > nrows - 1) grow = nrows - 1;
        const float* src = &A[(size_t)grow * K_DIM + seg];
        _Float16 hi[32], lo[32];
        #pragma unroll
        for (int i = 0; i < 8; ++i) {
            float4 v = *(const float4*)&src[i * 4];
            const float vf[4] = {v.x, v.y, v.z, v.w};
            #pragma unroll
            for (int j = 0; j < 4; ++j) {
                _Float16 h = (_Float16)vf[j];
                hi[i * 4 + j] = h;
                lo[i * 4 + j] = (_Float16)(vf[j] - (float)h);
            }
        }
        #pragma unroll
        for (int c = 0; c < 4; ++c) {
            *(half8*)&Ah[r * LDA + seg + c * 8] = *(half8*)&hi[c * 8];
            *(half8*)&Al[r * LDA + seg + c * 8] = *(half8*)&lo[c * 8];
        }
    }
    {   // stage B: 128x128 halfs = 2048 b128-chunks, 8 per thread
        const _Float16* wf = (const _Float16*)Wh;
        #pragma unroll
        for (int i = 0; i < 8; ++i) {
            const int id = i * 256 + t;
            const int n = id >> 4, kc = id & 15;
            *(half8*)&Bh[n * LDA + kc * 8] = *(const half8*)&wf[n * 128 + kc * 8];
        }
    }
    __syncthreads();

    const int lane = t & 63, wave = t >> 6;
    const int m = lane & 15, quad = lane >> 4;
    const int arow = wave * 16 + m;

    floatx4 acc[8];
    #pragma unroll
    for (int nt = 0; nt < 8; ++nt) acc[nt] = (floatx4){0.f, 0.f, 0.f, 0.f};

    #pragma unroll
    for (int k0 = 0; k0 < 128; k0 += 32) {
        half8 ah = *(const half8*)&Ah[arow * LDA + k0 + quad * 8];
        half8 al = *(const half8*)&Al[arow * LDA + k0 + quad * 8];
        #pragma unroll
        for (int nt = 0; nt < 8; ++nt) {
            half8 b = *(const half8*)&Bh[(nt * 16 + m) * LDA + k0 + quad * 8];
            acc[nt] = __builtin_amdgcn_mfma_f32_16x16x32_f16(ah, b, acc[nt], 0, 0, 0);
            acc[nt] = __builtin_amdgcn_mfma_f32_16x16x32_f16(al, b, acc[nt], 0, 0, 0);
        }
    }

    // D: row = quad*4 + reg, col = nt*16 + m
    #pragma unroll
    for (int reg = 0; reg < 4; ++reg) {
        const int row = row0 + wave * 16 + quad * 4 + reg;
        if (row < nrows) {
            const float nr = norm[row];
            #pragma unroll
            for (int nt = 0; nt < 8; ++nt)
                Hout[(size_t)row * 128 + nt * 16 + m] = __float2half(acc[nt][reg] * nr);
        }
    }
}

// Layer-2 MFMA GEMM: H'[row,0..63] = norm[row]*(agg1h[row,:]@W2), fp16 out.
// A input is fp16 (exact-as-stored); W2h fp16 [n][k].
__global__ __launch_bounds__(256) void gemm64_mfma(
    const __half* __restrict__ A, const __half* __restrict__ Wh,
    const float* __restrict__ norm, __half* __restrict__ Hout, int nrows)
{
    __shared__ _Float16 Ah[64 * LDA];
    __shared__ _Float16 Bh[64 * LDA];
    const int t = threadIdx.x;
    const int row0 = blockIdx.x * 64;
    const _Float16* af = (const _Float16*)A;
    const _Float16* wf = (const _Float16*)Wh;

    {   // stage A: 64x128 halfs = 1024 chunks, 4 per thread
        #pragma unroll
        for (int i = 0; i < 4; ++i) {
            const int id = i * 256 + t;
            const int r = id >> 4, kc = id & 15;
            int grow = row0 + r;
            if (grow > nrows - 1) grow = nrows - 1;
            *(half8*)&Ah[r * LDA + kc * 8] = *(const half8*)&af[(size_t)grow * 128 + kc * 8];
        }
    }
    {   // stage B: 64x128 halfs = 1024 chunks, 4 per thread
        #pragma unroll
        for (int i = 0; i < 4; ++i) {
            const int id = i * 256 + t;
            const int n = id >> 4, kc = id & 15;
            *(half8*)&Bh[n * LDA + kc * 8] = *(const half8*)&wf[n * 128 + kc * 8];
        }
    }
    __syncthreads();

    const int lane = t & 63, wave = t >> 6;
    const int m = lane & 15, quad = lane >> 4;
    const int arow = wave * 16 + m;

    floatx4 acc[4];
    #pragma unroll
    for (int nt = 0; nt < 4; ++nt) acc[nt] = (floatx4){0.f, 0.f, 0.f, 0.f};

    #pragma unroll
    for (int k0 = 0; k0 < 128; k0 += 32) {
        half8 ah = *(const half8*)&Ah[arow * LDA + k0 + quad * 8];
        #pragma unroll
        for (int nt = 0; nt < 4; ++nt) {
            half8 b = *(const half8*)&Bh[(nt * 16 + m) * LDA + k0 + quad * 8];
            acc[nt] = __builtin_amdgcn_mfma_f32_16x16x32_f16(ah, b, acc[nt], 0, 0, 0);
        }
    }

    #pragma unroll
    for (int reg = 0; reg < 4; ++reg) {
        const int row = row0 + wave * 16 + quad * 4 + reg;
        if (row < nrows) {
            const float nr = norm[row];
            #pragma unroll
            for (int nt = 0; nt < 4; ++nt)
                Hout[(size_t)row * 64 + nt * 16 + m] = __float2half(acc[nt][reg] * nr);
        }
    }
}

// Layer-1 aggregation (scalar-path): d wave-uniform; csr via s_load; lane owns
// cols 2L,2L+1. Output agg fp16 [N x 128].
//   agg[d,:] = relu( nd * (sum_e h'[s_e,:] + h'[d,:]) + bias )
__global__ __launch_bounds__(256) void gather_relu_f16(
    const int* __restrict__ rowptr, const int* __restrict__ csr,
    const float* __restrict__ norm, const __half* __restrict__ h,
    const float* __restrict__ bias, __half* __restrict__ agg, int n)
{
    const int lane = threadIdx.x & 63;
    const int d = __builtin_amdgcn_readfirstlane(blockIdx.x * 4 + (threadIdx.x >> 6));
    if (d >= n) return;
    const __half2* hp = (const __half2*)h;   // row stride 64 half2 (256 B)

    const int jb = rowptr[d], je = rowptr[d + 1];
    float ax[8] = {}, ay[8] = {};
    int j = jb;
    if (j + 8 <= je) {
        int s[8];
        #pragma unroll
        for (int q = 0; q < 8; ++q) s[q] = csr[j + q];
        for (; j + 16 <= je; j += 8) {
            int sn[8];
            #pragma unroll
            for (int q = 0; q < 8; ++q) sn[q] = csr[j + 8 + q];
            #pragma unroll
            for (int q = 0; q < 8; ++q) {
                const float2 v = __half22float2(hp[(size_t)s[q] * 64 + lane]);
                ax[q] += v.x; ay[q] += v.y;
            }
            #pragma unroll
            for (int q = 0; q < 8; ++q) s[q] = sn[q];
        }
        #pragma unroll
        for (int q = 0; q < 8; ++q) {
            const float2 v = __half22float2(hp[(size_t)s[q] * 64 + lane]);
            ax[q] += v.x; ay[q] += v.y;
        }
        j += 8;
    }
    for (; j < je; ++j) {
        const float2 v = __half22float2(hp[(size_t)csr[j] * 64 + lane]);
        ax[0] += v.x; ay[0] += v.y;
    }

    const float2 sv = __half22float2(hp[(size_t)d * 64 + lane]);   // self (premult)
    const float nd = norm[d];
    float sx = ((ax[0] + ax[1]) + (ax[2] + ax[3])) + ((ax[4] + ax[5]) + (ax[6] + ax[7])) + sv.x;
    float sy = ((ay[0] + ay[1]) + (ay[2] + ay[3])) + ((ay[4] + ay[5]) + (ay[6] + ay[7])) + sv.y;
    const float ox = fmaxf(fmaf(nd, sx, bias[2 * lane]), 0.f);
    const float oy = fmaxf(fmaf(nd, sy, bias[2 * lane + 1]), 0.f);
    ((__half2*)agg)[(size_t)d * 64 + lane] = __floats2half2_rn(ox, oy);
}

// Layer-2 aggregation + row softmax (scalar-path); h' fp16, 64 cols = 64 lanes.
__global__ __launch_bounds__(256) void gather_softmax(
    const int* __restrict__ rowptr, const int* __restrict__ csr,
    const float* __restrict__ norm, const __half* __restrict__ h,
    const float* __restrict__ bias, float* __restrict__ out, int n)
{
    const int lane = threadIdx.x & 63;
    const int d = __builtin_amdgcn_readfirstlane(blockIdx.x * 4 + (threadIdx.x >> 6));
    if (d >= n) return;

    const int jb = rowptr[d], je = rowptr[d + 1];
    float acc[8] = {};
    int j = jb;
    if (j + 8 <= je) {
        int s[8];
        #pragma unroll
        for (int q = 0; q < 8; ++q) s[q] = csr[j + q];
        for (; j + 16 <= je; j += 8) {
            int sn[8];
            #pragma unroll
            for (int q = 0; q < 8; ++q) sn[q] = csr[j + 8 + q];
            #pragma unroll
            for (int q = 0; q < 8; ++q)
                acc[q] += __half2float(h[(size_t)s[q] * 64 + lane]);
            #pragma unroll
            for (int q = 0; q < 8; ++q) s[q] = sn[q];
        }
        #pragma unroll
        for (int q = 0; q < 8; ++q)
            acc[q] += __half2float(h[(size_t)s[q] * 64 + lane]);
        j += 8;
    }
    for (; j < je; ++j)
        acc[0] += __half2float(h[(size_t)csr[j] * 64 + lane]);

    const float nd = norm[d];
    float tot = ((acc[0] + acc[1]) + (acc[2] + acc[3])) +
                ((acc[4] + acc[5]) + (acc[6] + acc[7])) +
                __half2float(h[(size_t)d * 64 + lane]);
    float a = fmaf(nd, tot, bias[lane]);
    float m = a;
    #pragma unroll
    for (int off = 32; off; off >>= 1) m = fmaxf(m, __shfl_xor(m, off, 64));
    float ex = expf(a - m);
    float ssum = ex;
    #pragma unroll
    for (int off = 32; off; off >>= 1) ssum += __shfl_xor(ssum, off, 64);
    out[(size_t)d * 64 + lane] = ex / ssum;
}

extern "C" void kernel_launch(void* const* d_in, const int* in_sizes, int n_in,
                              void* d_out, int out_size, void* d_ws, size_t ws_size,
                              hipStream_t stream) {
    const float* x  = (const float*)d_in[0];
    const int*   ei = (const int*)d_in[1];
    const float* W1 = (const float*)d_in[2];
    const float* b1 = (const float*)d_in[3];
    const float* W2 = (const float*)d_in[4];
    const float* b2 = (const float*)d_in[5];
    float* out = (float*)d_out;

    const int N = in_sizes[0] / K_DIM;     // 100000 (<= 2^17 required)
    const int E = in_sizes[1] / 2;         // 1600000
    const int NBUCK = (N + 1023) >> 10;    // 98 buckets of 1024 nodes

    // Workspace layout (peak ~65 MB)
    size_t o = 0;
    char* base = (char*)d_ws;
    auto alloc = [&](size_t elems) {       // elems in 4-byte units
        void* p = base + o;
        o += (elems * 4 + 1023) & ~(size_t)1023;
        return p;
    };
    int*    bcount = (int*)   alloc(NB_MAX);
    int*    bbase  = (int*)   alloc(NB_MAX + 1);
    int*    bcur   = (int*)   alloc(NB_MAX);
    int*    rowptr = (int*)   alloc(N + 1);
    float*  norm   = (float*) alloc(N);
    int*    packed = (int*)   alloc(E);
    int*    csr    = (int*)   alloc(E);
    __half* W1h    = (__half*)alloc(128 * 128 / 2);
    __half* W2h    = (__half*)alloc(64 * 128 / 2);
    void*   bufA   = alloc((size_t)N * 64);          // h1h fp16 [Nx128] / h2h fp16 [Nx64]
    __half* agg1h  = (__half*)alloc((size_t)N * 64); // fp16 [Nx128]

    __half* h1h = (__half*)bufA;
    __half* h2h = (__half*)bufA;

    const int nb_c = (E + PART_CHUNK - 1) / PART_CHUNK;   // partition chunks
    const int nb_g = (N + 3) / 4;
    const int nb_m = (N + 63) / 64;

    // ---- CSR build (two-level partition) + weight prep ----
    zero_small<<<1, NB_MAX, 0, stream>>>(bcount);
    prep_weights<<<96, 256, 0, stream>>>(W1, W2, W1h, W2h);
    hist_buckets<<<nb_c, 256, 0, stream>>>(ei + E, E, bcount);
    scan_buckets<<<1, 64, 0, stream>>>(bcount, bbase, bcur, rowptr, N, E);
    partition_edges<<<nb_c, 256, 0, stream>>>(ei, E, bcur, packed);
    build_csr<<<NBUCK, 1024, 0, stream>>>(packed, bbase, N, rowptr, norm, csr);

    // ---- Layer 1: h1' = norm .* (x@W1), fp16 [N x 128], MFMA split-A ----
    gemm128_mfma<<<nb_m, 256, 0, stream>>>(x, W1h, norm, h1h, N);
    gather_relu_f16<<<nb_g, 256, 0, stream>>>(rowptr, csr, norm, h1h, b1, agg1h, N);

    // ---- Layer 2: h2' = norm .* (agg1@W2), fp16 [N x 64], MFMA ----
    gemm64_mfma<<<nb_m, 256, 0, stream>>>(agg1h, W2h, norm, h2h, N);
    gather_softmax<<<nb_g, 256, 0, stream>>>(rowptr, csr, norm, h2h, b2, out, N);
}